// Round 1
// baseline (601.131 us; speedup 1.0000x reference)
//
#include <hip/hip_runtime.h>
#include <math.h>

#define Kn 4
#define Mm 128
#define Dd 64
#define Tt 256
#define Nn 254        // T-2
#define Cc 512        // Kn*Mm
#define ZSTRIDE 16384 // D*T
#define LD 256        // L row stride (padded)
#define LSZ 65536     // per-d L buffer (256x256)

// ws float offsets
#define AMU0_OFF (Dd*LSZ)
#define AMU1_OFF (AMU0_OFF + Dd*256)
#define PLD_OFF  (AMU1_OFF + Dd*256)

// ---------------- K1: build Sigma (into L buffer) + A_mu ----------------
__global__ __launch_bounds__(256) void k_build(const float* __restrict__ log_tau,
                                               float* __restrict__ ws) {
  const int d = blockIdx.x;
  const int tid = threadIdx.x;
  __shared__ float g[256];
  __shared__ float a0s[256], a1s[256];
  float tau = expf(log_tau[d]);
  float inv2 = 1.0f / (2.0f * tau * tau);
  float l = (float)tid;
  g[tid] = expf(-(l * l) * inv2);
  __syncthreads();
  float b = g[255];
  float det = 1.0f - b * b;
  float* Amu0 = ws + AMU0_OFF + d * 256;
  float* Amu1 = ws + AMU1_OFF + d * 256;
  if (tid < Nn) {
    float kp0 = g[tid + 1], kp1 = g[254 - tid];
    float a0 = (kp0 - b * kp1) / det;
    float a1 = (kp1 - b * kp0) / det;
    a0s[tid] = a0; a1s[tid] = a1;
    Amu0[tid] = a0; Amu1[tid] = a1;
  } else {
    a0s[tid] = 0.f; a1s[tid] = 0.f; Amu0[tid] = 0.f; Amu1[tid] = 0.f;
  }
  __syncthreads();
  float* A = ws + d * LSZ;
  for (int e = tid; e < LSZ; e += 256) {
    int t = e >> 8, s = e & 255;
    float v = 0.f;
    if (t < Nn && s < Nn) {
      int lag = t - s; lag = lag < 0 ? -lag : lag;
      v = g[lag] - a0s[t] * g[s + 1] - a1s[t] * g[254 - s];
      if (t == s) v += 1e-5f;
    }
    A[e] = v;
  }
}

// ---------------- K2: blocked Cholesky, one block per d ----------------
#define PB 32
#define PSTRIDE 260   // multiple of 4 (16B-aligned cols), mod 32 == 4

__global__ __launch_bounds__(256) void k_chol(float* __restrict__ ws) {
  const int d = blockIdx.x;
  const int tid = threadIdx.x;
  float* A = ws + d * LSZ;
  __shared__ float P[PB * PSTRIDE];   // col-major panel: P[c*PSTRIDE + r]
  __shared__ float diag_s[PB], rd_s[PB], logv[PB];
  __shared__ float logtot;
  if (tid == 0) logtot = 0.f;

  for (int p = 0; p < 8; ++p) {
    const int j0 = p * PB;
    const int m = Nn - j0;                    // rows in panel (local 0..m-1)
    const int bw = (m < PB) ? m : PB;         // valid columns
    __syncthreads();
    // load panel (coalesced rows)
    for (int e = tid; e < PB * m; e += 256) {
      int r = e >> 5, c = e & 31;
      P[c * PSTRIDE + r] = A[(j0 + r) * LD + j0 + c];
    }
    __syncthreads();
    // factor with delayed scaling: one barrier per column
    for (int j = 0; j < bw; ++j) {
      float pjj = P[j * PSTRIDE + j];
      float invp = 1.0f / pjj;
      int nc = bw - 1 - j;
      int mr = m - 1 - j;
      int tot = nc * mr;
      for (int e = tid; e < tot; e += 256) {
        int r = j + 1 + e / nc;
        int c = j + 1 + e % nc;
        P[c * PSTRIDE + r] -= P[j * PSTRIDE + r] * P[j * PSTRIDE + c] * invp;
      }
      __syncthreads();
    }
    // diag, reciprocals, log-accumulate
    if (tid < bw) {
      float pjj = P[tid * PSTRIDE + tid];
      float dj = sqrtf(pjj);
      diag_s[tid] = dj;
      rd_s[tid] = 1.0f / dj;
      logv[tid] = 0.5f * logf(fabsf(pjj));
    }
    __syncthreads();
    if (tid == 0) {
      float s = logtot;
      for (int j2 = 0; j2 < bw; ++j2) s += logv[j2];
      logtot = s;
    }
    // scale columns to true L values
    for (int e = tid; e < PB * m; e += 256) {
      int r = e >> 5, c = e & 31;
      if (c < bw) {
        if (r > c)      P[c * PSTRIDE + r] *= rd_s[c];
        else if (r == c) P[c * PSTRIDE + r] = diag_s[c];
      }
    }
    __syncthreads();
    // trailing SYRK update: A[i][k] -= sum_j L[i][j]*L[k][j], global RMW
    const int tb = j0 + PB;
    if (tb < Nn) {
      const int ti4 = (tid >> 4) * 4, tk4 = (tid & 15) * 4;
      for (int I0 = tb; I0 < Nn; I0 += 64) {
        for (int K0 = tb; K0 <= I0 + 63 && K0 < Nn; K0 += 64) {
          int i_ = I0 + ti4;
          int k_ = K0 + tk4;
          if (i_ > 255) continue;
          if (k_ > 252) continue;
          if (k_ > i_ + 3) continue;
          int ri = i_ - j0, rk = k_ - j0;
          float acc[4][4] = {};
          for (int j = 0; j < bw; ++j) {
            float4 pi = *(const float4*)&P[j * PSTRIDE + ri];
            float4 pk = *(const float4*)&P[j * PSTRIDE + rk];
            acc[0][0] += pi.x * pk.x; acc[0][1] += pi.x * pk.y; acc[0][2] += pi.x * pk.z; acc[0][3] += pi.x * pk.w;
            acc[1][0] += pi.y * pk.x; acc[1][1] += pi.y * pk.y; acc[1][2] += pi.y * pk.z; acc[1][3] += pi.y * pk.w;
            acc[2][0] += pi.z * pk.x; acc[2][1] += pi.z * pk.y; acc[2][2] += pi.z * pk.z; acc[2][3] += pi.z * pk.w;
            acc[3][0] += pi.w * pk.x; acc[3][1] += pi.w * pk.y; acc[3][2] += pi.w * pk.z; acc[3][3] += pi.w * pk.w;
          }
          for (int a2 = 0; a2 < 4; ++a2) {
            int irow = i_ + a2;
            if (irow > 255) break;
            float4* ap = (float4*)&A[irow * LD + k_];
            float4 v = *ap;
            v.x -= acc[a2][0]; v.y -= acc[a2][1]; v.z -= acc[a2][2]; v.w -= acc[a2][3];
            *ap = v;
          }
        }
      }
    }
    // write back panel (zeros above diagonal / invalid cols)
    for (int e = tid; e < PB * m; e += 256) {
      int r = e >> 5, c = e & 31;
      float v = 0.f;
      if (c < bw && r >= c) v = P[c * PSTRIDE + r];
      A[(j0 + r) * LD + j0 + c] = v;
    }
  }
  __syncthreads();
  if (tid == 0) ws[PLD_OFF + d] = logtot;
}

// ---------------- K3: logdet reduce + scalar output ----------------
__global__ void k_logdet(const float* __restrict__ ws, const float* __restrict__ sldj,
                         float* __restrict__ out) {
  int tid = threadIdx.x;  // 64 threads, one wave
  float v = ws[PLD_OFF + tid];
  for (int off = 32; off > 0; off >>= 1) v += __shfl_down(v, off);
  if (tid == 0) out[Cc * ZSTRIDE / 1] = 0.f;  // placeholder overwritten below (keeps compiler honest)
  if (tid == 0) out[8388608] = sldj[0] + v;
}

// ---------------- K4: out[t,c] = sum_s L[t,s]*zmid[s,c] + mu ----------------
#define LTS 132  // LDS row stride for 16 x 128 tiles

__global__ __launch_bounds__(256) void k_gemm(const float* __restrict__ z,
                                              const float* __restrict__ ws,
                                              float* __restrict__ out) {
  const int d = blockIdx.z;
  const int t0 = blockIdx.y * 128;
  const int c0 = blockIdx.x * 128;
  const int tid = threadIdx.x;
  const float* A = ws + d * LSZ;
  __shared__ float Lt[16 * LTS];   // [s][t]
  __shared__ float Zt[16 * LTS];   // [s][c]
  float acc[8][8] = {};
  const int tt = tid & 15;   // t micro index
  const int tc = tid >> 4;   // c micro index

  const int nk = (blockIdx.y == 0) ? 8 : 16;
  for (int kt = 0; kt < nk; ++kt) {
    const int s0 = kt * 16;
    // stage L (transpose to [s][t]); mask s>t only on near-diagonal tiles
    {
      const int row = tid >> 2;
      const int sq = (tid & 3) * 4;
      const bool needmask = (s0 + 15 > t0);
      for (int h = 0; h < 2; ++h) {
        int gt = t0 + row + h * 64;   // <= 255, in-buffer
        float4 l4 = *(const float4*)&A[gt * LD + s0 + sq];
        if (needmask) {
          if (s0 + sq + 0 > gt) l4.x = 0.f;
          if (s0 + sq + 1 > gt) l4.y = 0.f;
          if (s0 + sq + 2 > gt) l4.z = 0.f;
          if (s0 + sq + 3 > gt) l4.w = 0.f;
        }
        Lt[(sq + 0) * LTS + row + h * 64] = l4.x;
        Lt[(sq + 1) * LTS + row + h * 64] = l4.y;
        Lt[(sq + 2) * LTS + row + h * 64] = l4.z;
        Lt[(sq + 3) * LTS + row + h * 64] = l4.w;
      }
    }
    // stage Z: lanes along s for coalescing (z offset is +1 -> scalar loads)
    {
      const int sidx = tid & 15;
      const int cpart = tid >> 4;
      int sg = s0 + sidx;
      bool ok = (sg <= 253);
      for (int cl = 0; cl < 8; ++cl) {
        int gc = c0 + cpart * 8 + cl;
        float v = ok ? z[gc * ZSTRIDE + d * Tt + 1 + sg] : 0.f;
        Zt[sidx * LTS + cpart * 8 + cl] = v;
      }
    }
    __syncthreads();
#pragma unroll
    for (int s = 0; s < 16; ++s) {
      float4 la = *(const float4*)&Lt[s * LTS + 8 * tt];
      float4 lb = *(const float4*)&Lt[s * LTS + 8 * tt + 4];
      float4 za = *(const float4*)&Zt[s * LTS + 8 * tc];
      float4 zb = *(const float4*)&Zt[s * LTS + 8 * tc + 4];
      float lv[8] = {la.x, la.y, la.z, la.w, lb.x, lb.y, lb.z, lb.w};
      float zv[8] = {za.x, za.y, za.z, za.w, zb.x, zb.y, zb.z, zb.w};
#pragma unroll
      for (int a2 = 0; a2 < 8; ++a2)
#pragma unroll
        for (int b2 = 0; b2 < 8; ++b2)
          acc[a2][b2] += lv[a2] * zv[b2];
    }
    __syncthreads();
  }

  // epilogue: + Amu0[t]*z[..,0] + Amu1[t]*z[..,255], then store
  const float* Amu0 = ws + AMU0_OFF + d * 256;
  const float* Amu1 = ws + AMU1_OFF + d * 256;
  float a0v[8], a1v[8], ze0[8], ze1[8];
#pragma unroll
  for (int i = 0; i < 8; ++i) {
    int t_ = t0 + 8 * tt + i;
    a0v[i] = Amu0[t_];
    a1v[i] = Amu1[t_];
  }
#pragma unroll
  for (int j = 0; j < 8; ++j) {
    int c_ = c0 + 8 * tc + j;
    ze0[j] = z[c_ * ZSTRIDE + d * Tt];
    ze1[j] = z[c_ * ZSTRIDE + d * Tt + 255];
  }
#pragma unroll
  for (int i = 0; i < 8; ++i)
#pragma unroll
    for (int j = 0; j < 8; ++j)
      acc[i][j] += a0v[i] * ze0[j] + a1v[i] * ze1[j];

#pragma unroll
  for (int j = 0; j < 8; ++j) {
    int c_ = c0 + 8 * tc + j;
    float* op = out + c_ * ZSTRIDE + d * Tt + 1 + t0 + 8 * tt;
#pragma unroll
    for (int i = 0; i < 8; ++i) {
      int t_ = t0 + 8 * tt + i;
      if (t_ < Nn) op[i] = acc[i][j];
    }
  }
}

// ---------------- K5: endpoint passthrough ----------------
__global__ void k_edges(const float* __restrict__ z, float* __restrict__ out) {
  int id = blockIdx.x * 256 + threadIdx.x;  // 0..32767
  int c = id >> 6, d = id & 63;
  int base = c * ZSTRIDE + d * Tt;
  out[base] = z[base];
  out[base + 255] = z[base + 255];
}

extern "C" void kernel_launch(void* const* d_in, const int* in_sizes, int n_in,
                              void* d_out, int out_size, void* d_ws, size_t ws_size,
                              hipStream_t stream) {
  const float* z = (const float*)d_in[0];
  const float* sldj = (const float*)d_in[1];
  const float* log_tau = (const float*)d_in[2];
  float* out = (float*)d_out;
  float* ws = (float*)d_ws;

  hipLaunchKernelGGL(k_build, dim3(Dd), dim3(256), 0, stream, log_tau, ws);
  hipLaunchKernelGGL(k_chol, dim3(Dd), dim3(256), 0, stream, ws);
  hipLaunchKernelGGL(k_logdet, dim3(1), dim3(64), 0, stream, ws, sldj, out);
  hipLaunchKernelGGL(k_gemm, dim3(4, 2, Dd), dim3(256), 0, stream, z, ws, out);
  hipLaunchKernelGGL(k_edges, dim3(128), dim3(256), 0, stream, z, out);
}

// Round 2
// 378.080 us; speedup vs baseline: 1.5900x; 1.5900x over previous
//
#include <hip/hip_runtime.h>
#include <math.h>

#define Kn 4
#define Mm 128
#define Dd 64
#define Tt 256
#define Nn 254        // T-2
#define Cc 512        // Kn*Mm
#define ZSTRIDE 16384 // D*T
#define LD 256        // L row stride (padded)
#define LSZ 65536     // per-d L buffer (256x256)

// ws float offsets
#define AMU0_OFF (Dd*LSZ)
#define AMU1_OFF (AMU0_OFF + Dd*256)
#define PLD_OFF  (AMU1_OFF + Dd*256)

// ---------------- K1: build Sigma (into L buffer) + A_mu ----------------
__global__ __launch_bounds__(256) void k_build(const float* __restrict__ log_tau,
                                               float* __restrict__ ws) {
  const int d = blockIdx.x;
  const int tid = threadIdx.x;
  __shared__ float g[256];
  __shared__ float a0s[256], a1s[256];
  float tau = expf(log_tau[d]);
  float inv2 = 1.0f / (2.0f * tau * tau);
  float l = (float)tid;
  g[tid] = expf(-(l * l) * inv2);
  __syncthreads();
  float b = g[255];
  float det = 1.0f - b * b;
  float* Amu0 = ws + AMU0_OFF + d * 256;
  float* Amu1 = ws + AMU1_OFF + d * 256;
  if (tid < Nn) {
    float kp0 = g[tid + 1], kp1 = g[254 - tid];
    float a0 = (kp0 - b * kp1) / det;
    float a1 = (kp1 - b * kp0) / det;
    a0s[tid] = a0; a1s[tid] = a1;
    Amu0[tid] = a0; Amu1[tid] = a1;
  } else {
    a0s[tid] = 0.f; a1s[tid] = 0.f; Amu0[tid] = 0.f; Amu1[tid] = 0.f;
  }
  __syncthreads();
  float* A = ws + d * LSZ;
  for (int e = tid; e < LSZ; e += 256) {
    int t = e >> 8, s = e & 255;
    float v = 0.f;
    if (t < Nn && s < Nn) {
      int lag = t - s; lag = lag < 0 ? -lag : lag;
      v = g[lag] - a0s[t] * g[s + 1] - a1s[t] * g[254 - s];
      if (t == s) v += 1e-5f;
    }
    A[e] = v;
  }
}

// ---------------- K2: blocked Cholesky, one block per d ----------------
// Right-looking blocked: 32x32 diag factor (delayed scaling, diag block only)
// -> scale diag block -> TRSM (thread-per-row, register forward-subst, no
// barriers) -> SYRK trailing update (global RMW). Panel col-major in LDS,
// stride 260: column access over r is conflict-free (banks (4c+r)%32).
#define PB 32
#define PSTRIDE 260   // multiple of 4 (16B-aligned rows-of-4), mod 32 == 4

__global__ __launch_bounds__(256) void k_chol(float* __restrict__ ws) {
  const int d = blockIdx.x;
  const int tid = threadIdx.x;
  float* A = ws + d * LSZ;
  __shared__ float P[PB * PSTRIDE];   // col-major panel: P[c*PSTRIDE + r]
  __shared__ float diag_s[PB], rd_s[PB], logv[PB];
  __shared__ float logtot;
  if (tid == 0) logtot = 0.f;

  const int r32 = tid & 31;   // row lane within diag block
  const int cg  = tid >> 5;   // column group 0..7

  for (int p = 0; p < 8; ++p) {
    const int j0 = p * PB;
    const int m = Nn - j0;                    // rows in panel (local 0..m-1)
    const int bw = (m < PB) ? m : PB;         // valid columns
    __syncthreads();
    // load panel (coalesced rows)
    for (int e = tid; e < PB * m; e += 256) {
      int r = e >> 5, c = e & 31;
      P[c * PSTRIDE + r] = A[(j0 + r) * LD + j0 + c];
    }
    __syncthreads();

    // ---- factor 32x32 diag block (delayed scaling), lower triangle only ----
    for (int j = 0; j < bw; ++j) {
      float invp = 1.0f / P[j * PSTRIDE + j];       // broadcast read
      float prj = P[j * PSTRIDE + r32];             // conflict-free, hoisted
      float s = prj * invp;
#pragma unroll
      for (int k = 0; k < 4; ++k) {
        int c = j + 1 + cg + 8 * k;
        if (c < bw && r32 >= c) {
          P[c * PSTRIDE + r32] -= s * P[j * PSTRIDE + c];  // col val: broadcast
        }
      }
      __syncthreads();
    }

    // ---- diag, reciprocals, log-accumulate ----
    if (tid < bw) {
      float pjj = P[tid * PSTRIDE + tid];
      float dj = sqrtf(pjj);
      diag_s[tid] = dj;
      rd_s[tid] = 1.0f / dj;
      logv[tid] = 0.5f * logf(fabsf(pjj));
    }
    __syncthreads();
    if (tid == 0) {
      float s = logtot;
      for (int j2 = 0; j2 < bw; ++j2) s += logv[j2];
      logtot = s;
    }
    // ---- scale diag block to true L (zero its upper triangle) ----
    for (int c = cg; c < bw; c += 8) {
      if (r32 < bw) {
        float v = P[c * PSTRIDE + r32];
        if (r32 > c)       v *= rd_s[c];
        else if (r32 == c) v = diag_s[c];
        else               v = 0.f;
        P[c * PSTRIDE + r32] = v;
      }
    }
    __syncthreads();

    // ---- TRSM: rows bw..m-1, one thread per row, no barriers ----
    const int nrows = m - bw;   // <=222, single pass
    if (tid < nrows) {
      const int ri = bw + tid;
      float a[PB];
#pragma unroll
      for (int c = 0; c < PB; ++c) a[c] = P[c * PSTRIDE + ri];
#pragma unroll
      for (int j = 0; j < PB; ++j) {
        a[j] *= rd_s[j];
#pragma unroll
        for (int k = j + 1; k < PB; ++k)
          a[k] -= a[j] * P[j * PSTRIDE + k];   // L[k][j], broadcast
      }
#pragma unroll
      for (int c = 0; c < PB; ++c) P[c * PSTRIDE + ri] = a[c];
    }
    __syncthreads();

    // ---- trailing SYRK update: A[i][k] -= sum_j L[i][j]*L[k][j] ----
    const int tb = j0 + PB;
    if (tb < Nn) {
      const int ti4 = (tid >> 4) * 4, tk4 = (tid & 15) * 4;
      for (int I0 = tb; I0 < Nn; I0 += 64) {
        for (int K0 = tb; K0 <= I0 + 63 && K0 < Nn; K0 += 64) {
          int i_ = I0 + ti4;
          int k_ = K0 + tk4;
          if (i_ > 255) continue;
          if (k_ > 252) continue;
          if (k_ > i_ + 3) continue;
          int ri = i_ - j0, rk = k_ - j0;
          float acc[4][4] = {};
          for (int j = 0; j < PB; ++j) {
            float4 pi = *(const float4*)&P[j * PSTRIDE + ri];
            float4 pk = *(const float4*)&P[j * PSTRIDE + rk];
            acc[0][0] += pi.x * pk.x; acc[0][1] += pi.x * pk.y; acc[0][2] += pi.x * pk.z; acc[0][3] += pi.x * pk.w;
            acc[1][0] += pi.y * pk.x; acc[1][1] += pi.y * pk.y; acc[1][2] += pi.y * pk.z; acc[1][3] += pi.y * pk.w;
            acc[2][0] += pi.z * pk.x; acc[2][1] += pi.z * pk.y; acc[2][2] += pi.z * pk.z; acc[2][3] += pi.z * pk.w;
            acc[3][0] += pi.w * pk.x; acc[3][1] += pi.w * pk.y; acc[3][2] += pi.w * pk.z; acc[3][3] += pi.w * pk.w;
          }
          for (int a2 = 0; a2 < 4; ++a2) {
            int irow = i_ + a2;
            if (irow > 255) break;
            float4* ap = (float4*)&A[irow * LD + k_];
            float4 v = *ap;
            v.x -= acc[a2][0]; v.y -= acc[a2][1]; v.z -= acc[a2][2]; v.w -= acc[a2][3];
            *ap = v;
          }
        }
      }
    }
    // ---- write back panel (diag upper already zeroed in LDS) ----
    for (int e = tid; e < PB * m; e += 256) {
      int r = e >> 5, c = e & 31;
      A[(j0 + r) * LD + j0 + c] = P[c * PSTRIDE + r];
    }
  }
  __syncthreads();
  if (tid == 0) ws[PLD_OFF + d] = logtot;
}

// ---------------- K3: logdet reduce + scalar output ----------------
__global__ void k_logdet(const float* __restrict__ ws, const float* __restrict__ sldj,
                         float* __restrict__ out) {
  int tid = threadIdx.x;  // 64 threads, one wave
  float v = ws[PLD_OFF + tid];
  for (int off = 32; off > 0; off >>= 1) v += __shfl_down(v, off);
  if (tid == 0) out[8388608] = sldj[0] + v;   // Cc*ZSTRIDE
}

// ---------------- K4: out[t,c] = sum_s L[t,s]*zmid[s,c] + mu ----------------
#define LTS 132  // LDS row stride for 16 x 128 tiles

__global__ __launch_bounds__(256) void k_gemm(const float* __restrict__ z,
                                              const float* __restrict__ ws,
                                              float* __restrict__ out) {
  const int d = blockIdx.z;
  const int t0 = blockIdx.y * 128;
  const int c0 = blockIdx.x * 128;
  const int tid = threadIdx.x;
  const float* A = ws + d * LSZ;
  __shared__ float Lt[16 * LTS];   // [s][t]
  __shared__ float Zt[16 * LTS];   // [s][c]
  float acc[8][8] = {};
  const int tt = tid & 15;   // t micro index
  const int tc = tid >> 4;   // c micro index

  const int nk = (blockIdx.y == 0) ? 8 : 16;
  for (int kt = 0; kt < nk; ++kt) {
    const int s0 = kt * 16;
    // stage L (transpose to [s][t]); mask s>t only on near-diagonal tiles
    {
      const int row = tid >> 2;
      const int sq = (tid & 3) * 4;
      const bool needmask = (s0 + 15 > t0);
      for (int h = 0; h < 2; ++h) {
        int gt = t0 + row + h * 64;   // <= 255, in-buffer
        float4 l4 = *(const float4*)&A[gt * LD + s0 + sq];
        if (needmask) {
          if (s0 + sq + 0 > gt) l4.x = 0.f;
          if (s0 + sq + 1 > gt) l4.y = 0.f;
          if (s0 + sq + 2 > gt) l4.z = 0.f;
          if (s0 + sq + 3 > gt) l4.w = 0.f;
        }
        Lt[(sq + 0) * LTS + row + h * 64] = l4.x;
        Lt[(sq + 1) * LTS + row + h * 64] = l4.y;
        Lt[(sq + 2) * LTS + row + h * 64] = l4.z;
        Lt[(sq + 3) * LTS + row + h * 64] = l4.w;
      }
    }
    // stage Z: lanes along s for coalescing (z offset is +1 -> scalar loads)
    {
      const int sidx = tid & 15;
      const int cpart = tid >> 4;
      int sg = s0 + sidx;
      bool ok = (sg <= 253);
      for (int cl = 0; cl < 8; ++cl) {
        int gc = c0 + cpart * 8 + cl;
        float v = ok ? z[gc * ZSTRIDE + d * Tt + 1 + sg] : 0.f;
        Zt[sidx * LTS + cpart * 8 + cl] = v;
      }
    }
    __syncthreads();
#pragma unroll
    for (int s = 0; s < 16; ++s) {
      float4 la = *(const float4*)&Lt[s * LTS + 8 * tt];
      float4 lb = *(const float4*)&Lt[s * LTS + 8 * tt + 4];
      float4 za = *(const float4*)&Zt[s * LTS + 8 * tc];
      float4 zb = *(const float4*)&Zt[s * LTS + 8 * tc + 4];
      float lv[8] = {la.x, la.y, la.z, la.w, lb.x, lb.y, lb.z, lb.w};
      float zv[8] = {za.x, za.y, za.z, za.w, zb.x, zb.y, zb.z, zb.w};
#pragma unroll
      for (int a2 = 0; a2 < 8; ++a2)
#pragma unroll
        for (int b2 = 0; b2 < 8; ++b2)
          acc[a2][b2] += lv[a2] * zv[b2];
    }
    __syncthreads();
  }

  // epilogue: + Amu0[t]*z[..,0] + Amu1[t]*z[..,255], then store
  const float* Amu0 = ws + AMU0_OFF + d * 256;
  const float* Amu1 = ws + AMU1_OFF + d * 256;
  float a0v[8], a1v[8], ze0[8], ze1[8];
#pragma unroll
  for (int i = 0; i < 8; ++i) {
    int t_ = t0 + 8 * tt + i;
    a0v[i] = Amu0[t_];
    a1v[i] = Amu1[t_];
  }
#pragma unroll
  for (int j = 0; j < 8; ++j) {
    int c_ = c0 + 8 * tc + j;
    ze0[j] = z[c_ * ZSTRIDE + d * Tt];
    ze1[j] = z[c_ * ZSTRIDE + d * Tt + 255];
  }
#pragma unroll
  for (int i = 0; i < 8; ++i)
#pragma unroll
    for (int j = 0; j < 8; ++j)
      acc[i][j] += a0v[i] * ze0[j] + a1v[i] * ze1[j];

#pragma unroll
  for (int j = 0; j < 8; ++j) {
    int c_ = c0 + 8 * tc + j;
    float* op = out + c_ * ZSTRIDE + d * Tt + 1 + t0 + 8 * tt;
#pragma unroll
    for (int i = 0; i < 8; ++i) {
      int t_ = t0 + 8 * tt + i;
      if (t_ < Nn) op[i] = acc[i][j];
    }
  }
}

// ---------------- K5: endpoint passthrough ----------------
__global__ void k_edges(const float* __restrict__ z, float* __restrict__ out) {
  int id = blockIdx.x * 256 + threadIdx.x;  // 0..32767
  int c = id >> 6, d = id & 63;
  int base = c * ZSTRIDE + d * Tt;
  out[base] = z[base];
  out[base + 255] = z[base + 255];
}

extern "C" void kernel_launch(void* const* d_in, const int* in_sizes, int n_in,
                              void* d_out, int out_size, void* d_ws, size_t ws_size,
                              hipStream_t stream) {
  const float* z = (const float*)d_in[0];
  const float* sldj = (const float*)d_in[1];
  const float* log_tau = (const float*)d_in[2];
  float* out = (float*)d_out;
  float* ws = (float*)d_ws;

  hipLaunchKernelGGL(k_build, dim3(Dd), dim3(256), 0, stream, log_tau, ws);
  hipLaunchKernelGGL(k_chol, dim3(Dd), dim3(256), 0, stream, ws);
  hipLaunchKernelGGL(k_logdet, dim3(1), dim3(64), 0, stream, ws, sldj, out);
  hipLaunchKernelGGL(k_gemm, dim3(4, 2, Dd), dim3(256), 0, stream, z, ws, out);
  hipLaunchKernelGGL(k_edges, dim3(128), dim3(256), 0, stream, z, out);
}

// Round 4
// 296.908 us; speedup vs baseline: 2.0246x; 1.2734x over previous
//
#include <hip/hip_runtime.h>
#include <hip/hip_bf16.h>
#include <math.h>

#define Kn 4
#define Mm 128
#define Dd 64
#define Tt 256
#define Nn 254        // T-2
#define Cc 512        // Kn*Mm
#define ZSTRIDE 16384 // D*T
#define LD 256        // Sigma row stride
#define LSZ 65536     // per-d 256x256 buffer

// ws float offsets.  zb (bf16 [d][c][s], 16.78MB) OVERWRITES the fp32 Sigma/A
// region after k_chol finishes (A is dead by then) -> total ws = 25.3 MB.
#define AMU0_OFF 4194304              // 64*65536
#define AMU1_OFF 4210688
#define PLD_OFF  4227072
#define LB_OFF   4227136              // bf16 L, 64*65536 bf16

typedef __attribute__((ext_vector_type(8))) short short8;
typedef __attribute__((ext_vector_type(4))) float f32x4;

#define GLD16(g, l) __builtin_amdgcn_global_load_lds( \
    (const __attribute__((address_space(1))) void*)(g), \
    (__attribute__((address_space(3))) void*)(l), 16, 0, 0)

// ---------------- K1: build Sigma (fp32) + A_mu + zero bf16 L ----------------
__global__ __launch_bounds__(256) void k_build(const float* __restrict__ log_tau,
                                               float* __restrict__ ws) {
  const int d = blockIdx.x;
  const int tid = threadIdx.x;
  __shared__ float g[256];
  __shared__ float a0s[256], a1s[256];
  float tau = expf(log_tau[d]);
  float inv2 = 1.0f / (2.0f * tau * tau);
  float l = (float)tid;
  g[tid] = expf(-(l * l) * inv2);
  __syncthreads();
  float b = g[255];
  float det = 1.0f - b * b;
  float* Amu0 = ws + AMU0_OFF + d * 256;
  float* Amu1 = ws + AMU1_OFF + d * 256;
  if (tid < Nn) {
    float kp0 = g[tid + 1], kp1 = g[254 - tid];
    float a0 = (kp0 - b * kp1) / det;
    float a1 = (kp1 - b * kp0) / det;
    a0s[tid] = a0; a1s[tid] = a1;
    Amu0[tid] = a0; Amu1[tid] = a1;
  } else {
    a0s[tid] = 0.f; a1s[tid] = 0.f; Amu0[tid] = 0.f; Amu1[tid] = 0.f;
  }
  __syncthreads();
  float* A = ws + d * LSZ;
  for (int e = tid; e < LSZ; e += 256) {
    int t = e >> 8, s = e & 255;
    float v = 0.f;
    if (t < Nn && s < Nn) {
      int lag = t - s; lag = lag < 0 ? -lag : lag;
      v = g[lag] - a0s[t] * g[s + 1] - a1s[t] * g[254 - s];
      if (t == s) v += 1e-5f;
    }
    A[e] = v;
  }
  // zero bf16 L buffer (upper triangle / pad rows must be exact 0 for MFMA)
  unsigned int* lbz = (unsigned int*)(ws + LB_OFF) + d * (LSZ / 2);
  for (int i = tid; i < LSZ / 2; i += 256) lbz[i] = 0u;
}

// ---------------- K2: blocked Cholesky, one block per d ----------------
// Diag 32x32 factored in ONE WAVE's registers (row-per-lane, shfl broadcasts,
// no barriers); TRSM thread-per-row with float4 column reads; SYRK global RMW.
// 4 barriers/panel.  L emitted as bf16 (zeros above diag).
#define PB 32
#define PSTRIDE 260   // /4=65, 16B-aligned columns; (4c+r)%32 banks conflict-free over r

__global__ __launch_bounds__(256) void k_chol(float* __restrict__ ws) {
  const int d = blockIdx.x;
  const int tid = threadIdx.x;
  float* A = ws + d * LSZ;
  __hip_bfloat16* Lb = (__hip_bfloat16*)(ws + LB_OFF) + d * LSZ;
  __shared__ float P[PB * PSTRIDE];   // col-major: P[c*PSTRIDE + r]
  __shared__ float rd_s[PB], logv[PB];
  __shared__ float logtot;
  if (tid == 0) logtot = 0.f;

  for (int p = 0; p < 8; ++p) {
    const int j0 = p * PB;
    const int m = Nn - j0;
    const int bw = (m < PB) ? m : PB;
    __syncthreads();
    for (int e = tid; e < PB * m; e += 256) {
      int r = e >> 5, c = e & 31;
      P[c * PSTRIDE + r] = A[(j0 + r) * LD + j0 + c];
    }
    __syncthreads();

    // ---- phase A: single-wave register Cholesky (delayed scaling) ----
    if (tid < PB) {
      const int r = tid;
      float a[PB];
#pragma unroll
      for (int c = 0; c < PB; ++c) a[c] = P[c * PSTRIDE + r];
      float dr = 1.0f;
#pragma unroll
      for (int j = 0; j < PB; ++j) {
        float pj = __shfl(a[j], j);          // pivot d_j (lane j, reg j: lower ✓)
        if (r == j) dr = pj;
        float s = a[j] * (1.0f / pj);        // valid for lanes r>j (lower)
#pragma unroll
        for (int k = j + 1; k < PB; ++k)
          a[k] -= s * __shfl(a[j], k);       // a_k[j]: LOWER source (SYRK only maintains lower)
      }
      float rinv = 1.0f / sqrtf(dr);
      rd_s[r] = rinv;
      logv[r] = (r < bw) ? 0.5f * logf(fabsf(dr)) : 0.f;
      if (r < m) {
        __hip_bfloat16* lbrow = Lb + (j0 + r) * 256 + j0;
#pragma unroll
        for (int c = 0; c < PB; ++c) {
          float sc = __shfl(rinv, c);
          float v = 0.f;
          if (c < bw) {
            if (c < r)       v = a[c] * sc;
            else if (c == r) v = sqrtf(dr);
          }
          P[c * PSTRIDE + r] = v;
          lbrow[c] = __float2bfloat16(v);
        }
      }
    }
    __syncthreads();
    if (tid == 0) {
      float s = logtot;
      for (int j2 = 0; j2 < bw; ++j2) s += logv[j2];
      logtot = s;
    }

    // ---- TRSM: rows PB..m-1, thread-per-row, float4 column reads ----
    const int nrows = m - bw;               // >0 only when bw==PB
    if (tid < nrows) {
      const int ri = PB + tid;
      float a[PB];
#pragma unroll
      for (int c = 0; c < PB; ++c) a[c] = P[c * PSTRIDE + ri];
      const float4* P4 = (const float4*)P;
#pragma unroll
      for (int j = 0; j < PB; ++j) {
        float aj = a[j] * rd_s[j];
        a[j] = aj;
#pragma unroll
        for (int q = 0; q < PB / 4; ++q) {
          if (4 * q + 3 <= j) continue;     // compile-time prune
          float4 col = P4[j * (PSTRIDE / 4) + q];   // L[4q..4q+3][j], broadcast
          if (4 * q + 0 > j) a[4 * q + 0] -= aj * col.x;
          if (4 * q + 1 > j) a[4 * q + 1] -= aj * col.y;
          if (4 * q + 2 > j) a[4 * q + 2] -= aj * col.z;
          if (4 * q + 3 > j) a[4 * q + 3] -= aj * col.w;
        }
      }
      __hip_bfloat16* lbrow = Lb + (j0 + ri) * 256 + j0;
#pragma unroll
      for (int c = 0; c < PB; ++c) {
        P[c * PSTRIDE + ri] = a[c];
        lbrow[c] = __float2bfloat16(a[c]);
      }
    }
    __syncthreads();

    // ---- trailing SYRK: A[i][k] -= sum_j L[i][j]*L[k][j] (global RMW) ----
    const int tb = j0 + PB;
    if (tb < Nn) {
      const int ti4 = (tid >> 4) * 4, tk4 = (tid & 15) * 4;
      for (int I0 = tb; I0 < Nn; I0 += 64) {
        for (int K0 = tb; K0 <= I0 + 63 && K0 < Nn; K0 += 64) {
          int i_ = I0 + ti4;
          int k_ = K0 + tk4;
          if (i_ > 255) continue;
          if (k_ > 252) continue;
          if (k_ > i_ + 3) continue;
          int ri = i_ - j0, rk = k_ - j0;
          float acc[4][4] = {};
          for (int j = 0; j < PB; ++j) {
            float4 pi = *(const float4*)&P[j * PSTRIDE + ri];
            float4 pk = *(const float4*)&P[j * PSTRIDE + rk];
            acc[0][0] += pi.x * pk.x; acc[0][1] += pi.x * pk.y; acc[0][2] += pi.x * pk.z; acc[0][3] += pi.x * pk.w;
            acc[1][0] += pi.y * pk.x; acc[1][1] += pi.y * pk.y; acc[1][2] += pi.y * pk.z; acc[1][3] += pi.y * pk.w;
            acc[2][0] += pi.z * pk.x; acc[2][1] += pi.z * pk.y; acc[2][2] += pi.z * pk.z; acc[2][3] += pi.z * pk.w;
            acc[3][0] += pi.w * pk.x; acc[3][1] += pi.w * pk.y; acc[3][2] += pi.w * pk.z; acc[3][3] += pi.w * pk.w;
          }
          for (int a2 = 0; a2 < 4; ++a2) {
            int irow = i_ + a2;
            if (irow > 255) break;
            float4* ap = (float4*)&A[irow * LD + k_];
            float4 v = *ap;
            v.x -= acc[a2][0]; v.y -= acc[a2][1]; v.z -= acc[a2][2]; v.w -= acc[a2][3];
            *ap = v;
          }
        }
      }
    }
    // no fp32 panel writeback: bf16 Lb already written
  }
  __syncthreads();
  if (tid == 0) ws[PLD_OFF + d] = logtot;
}

// ---------------- K3: logdet reduce + scalar output ----------------
__global__ void k_logdet(const float* __restrict__ ws, const float* __restrict__ sldj,
                         float* __restrict__ out) {
  int tid = threadIdx.x;  // 64 threads
  float v = ws[PLD_OFF + tid];
  for (int off = 32; off > 0; off >>= 1) v += __shfl_down(v, off);
  if (tid == 0) out[8388608] = sldj[0] + v;   // Cc*ZSTRIDE
}

// ---------------- K3b: z -> bf16 [d][c][s] (overwrites dead Sigma region) + edges ----
__global__ __launch_bounds__(256) void k_zcast(const float* __restrict__ z,
                                               float* __restrict__ ws,
                                               float* __restrict__ out) {
  int rid = blockIdx.x * 4 + (threadIdx.x >> 6);   // 0..32767 = d*512 + c
  int lane = threadIdx.x & 63;
  int dd = rid >> 9, cc = rid & 511;
  const float* zr = z + cc * ZSTRIDE + dd * Tt;
  unsigned short* zbr = (unsigned short*)ws + (dd * 512 + cc) * 256;
#pragma unroll
  for (int i = 0; i < 4; ++i) {
    int s = lane + i * 64;
    float v = (s < Nn) ? zr[1 + s] : 0.f;
    __hip_bfloat16 b = __float2bfloat16(v);
    zbr[s] = *(unsigned short*)&b;
  }
  if (lane == 0) out[cc * ZSTRIDE + dd * Tt] = zr[0];
  if (lane == 1) out[cc * ZSTRIDE + dd * Tt + 255] = zr[255];
}

// ---------------- K4: MFMA bf16 GEMM: out[c,1+t] = sum_s z[c,s]*L[t,s] + mu ----
// A-operand = z tile [c][s], B-operand = L tile [t][s]; D: row=c (quad*4+reg),
// col=t (lane&15) -> coalesced stores along t.
__global__ __launch_bounds__(256) void k_gemm(const float* __restrict__ z,
                                              const float* __restrict__ ws,
                                              float* __restrict__ out) {
  const int d = blockIdx.z;
  const int t0 = blockIdx.y * 128;
  const int c0 = blockIdx.x * 128;
  const int tid = threadIdx.x;
  const unsigned short* zb = (const unsigned short*)ws + d * (512 * 256);
  const unsigned short* lb = (const unsigned short*)(ws + LB_OFF) + d * LSZ;
  __shared__ unsigned short As[128 * 32];   // [c][s] bf16
  __shared__ unsigned short Bs[128 * 32];   // [t][s] bf16
  f32x4 acc[4][4];
#pragma unroll
  for (int mi = 0; mi < 4; ++mi)
#pragma unroll
    for (int ni = 0; ni < 4; ++ni)
      acc[mi][ni] = (f32x4){0.f, 0.f, 0.f, 0.f};

  const int l = tid & 63, w = tid >> 6;
  const int wm = w & 1, wn = w >> 1;       // wave tile: c += wm*64, t += wn*64
  const int m16 = l & 15, quad = l >> 4;

  const int nks = (blockIdx.y == 0) ? 4 : 8;   // L[t<128][s>=128]==0 -> skip
  for (int ks = 0; ks < nks; ++ks) {
    const int s0 = ks * 32;
#pragma unroll
    for (int i = 0; i < 2; ++i) {
      int e = i * 256 + tid;
      int row = e >> 2, half = e & 3;      // 4x16B chunks per 32-bf16 row (FIXED)
      GLD16(zb + (c0 + row) * 256 + s0 + half * 8, &As[e * 8]);
      GLD16(lb + (t0 + row) * 256 + s0 + half * 8, &Bs[e * 8]);
    }
    __syncthreads();
    short8 af[4], bf[4];
#pragma unroll
    for (int mi = 0; mi < 4; ++mi)
      af[mi] = *(const short8*)&As[(wm * 64 + mi * 16 + m16) * 32 + quad * 8];
#pragma unroll
    for (int ni = 0; ni < 4; ++ni)
      bf[ni] = *(const short8*)&Bs[(wn * 64 + ni * 16 + m16) * 32 + quad * 8];
#pragma unroll
    for (int mi = 0; mi < 4; ++mi)
#pragma unroll
      for (int ni = 0; ni < 4; ++ni)
        acc[mi][ni] = __builtin_amdgcn_mfma_f32_16x16x32_bf16(af[mi], bf[ni], acc[mi][ni], 0, 0, 0);
    __syncthreads();
  }

  // epilogue: + Amu0[t]*z[c,0] + Amu1[t]*z[c,255]; store
  const float* Amu0 = ws + AMU0_OFF + d * 256;
  const float* Amu1 = ws + AMU1_OFF + d * 256;
  float a0v[4], a1v[4];
#pragma unroll
  for (int ni = 0; ni < 4; ++ni) {
    int t_ = t0 + wn * 64 + ni * 16 + m16;
    a0v[ni] = Amu0[t_]; a1v[ni] = Amu1[t_];
  }
#pragma unroll
  for (int mi = 0; mi < 4; ++mi) {
#pragma unroll
    for (int rg = 0; rg < 4; ++rg) {
      int c_ = c0 + wm * 64 + mi * 16 + quad * 4 + rg;
      const float* zc = z + c_ * ZSTRIDE + d * Tt;
      float z0 = zc[0], z1 = zc[255];
      float* op = out + c_ * ZSTRIDE + d * Tt + 1;
#pragma unroll
      for (int ni = 0; ni < 4; ++ni) {
        int t_ = t0 + wn * 64 + ni * 16 + m16;
        float v = acc[mi][ni][rg] + a0v[ni] * z0 + a1v[ni] * z1;
        if (t_ < Nn) op[t_] = v;
      }
    }
  }
}

extern "C" void kernel_launch(void* const* d_in, const int* in_sizes, int n_in,
                              void* d_out, int out_size, void* d_ws, size_t ws_size,
                              hipStream_t stream) {
  const float* z = (const float*)d_in[0];
  const float* sldj = (const float*)d_in[1];
  const float* log_tau = (const float*)d_in[2];
  float* out = (float*)d_out;
  float* ws = (float*)d_ws;

  hipLaunchKernelGGL(k_build, dim3(Dd), dim3(256), 0, stream, log_tau, ws);
  hipLaunchKernelGGL(k_chol, dim3(Dd), dim3(256), 0, stream, ws);
  hipLaunchKernelGGL(k_logdet, dim3(1), dim3(64), 0, stream, ws, sldj, out);
  hipLaunchKernelGGL(k_zcast, dim3(8192), dim3(256), 0, stream, z, ws, out);
  hipLaunchKernelGGL(k_gemm, dim3(4, 2, Dd), dim3(256), 0, stream, z, ws, out);
}

// Round 5
// 238.046 us; speedup vs baseline: 2.5253x; 1.2473x over previous
//
#include <hip/hip_runtime.h>
#include <hip/hip_bf16.h>
#include <math.h>

#define Kn 4
#define Mm 128
#define Dd 64
#define Tt 256
#define Nn 254        // T-2
#define Cc 512        // Kn*Mm
#define ZSTRIDE 16384 // D*T
#define LSZ 65536     // per-d 256x256 bf16 L (in ushorts)

// ws float offsets. zb bf16 [d][c][s] occupies [0, 4194304); Lb bf16 follows.
#define AMU0_OFF 4194304              // 64*65536
#define AMU1_OFF 4210688
#define PLD_OFF  4227072
#define LB_OFF   4227136              // bf16 L, 64*65536 ushorts = 2,097,152 floats

typedef __attribute__((ext_vector_type(8))) short short8;
typedef __attribute__((ext_vector_type(4))) float f32x4;

#define GLD16(g, l) __builtin_amdgcn_global_load_lds( \
    (const __attribute__((address_space(1))) void*)(g), \
    (__attribute__((address_space(3))) void*)(l), 16, 0, 0)

// ---------------- K0: zero bf16 L buffer ----------------
__global__ __launch_bounds__(256) void k_zero(float* __restrict__ ws) {
  int i = (blockIdx.x * 256 + threadIdx.x) * 4;
  *(float4*)(ws + LB_OFF + i) = (float4){0.f, 0.f, 0.f, 0.f};
}

// ---------------- K1: z -> bf16 [d][c][s] + edge passthrough ----------------
__global__ __launch_bounds__(256) void k_zcast(const float* __restrict__ z,
                                               float* __restrict__ ws,
                                               float* __restrict__ out) {
  int rid = blockIdx.x * 4 + (threadIdx.x >> 6);   // 0..32767 = d*512 + c
  int lane = threadIdx.x & 63;
  int dd = rid >> 9, cc = rid & 511;
  const float* zr = z + cc * ZSTRIDE + dd * Tt;
  unsigned short* zbr = (unsigned short*)ws + (dd * 512 + cc) * 256;
#pragma unroll
  for (int i = 0; i < 4; ++i) {
    int s = lane + i * 64;
    float v = (s < Nn) ? zr[1 + s] : 0.f;
    __hip_bfloat16 b = __float2bfloat16(v);
    zbr[s] = *(unsigned short*)&b;
  }
  if (lane == 0) out[cc * ZSTRIDE + dd * Tt] = zr[0];
  if (lane == 1) out[cc * ZSTRIDE + dd * Tt + 255] = zr[255];
}

// ---------------- K2: fused left-looking Cholesky, one block per d ----------------
// Per panel p (32 cols): each wave builds its 64x32 slab of the Schur panel in
// MFMA-C layout directly from the Sigma closed form, subtracts bf16-L history
// via mfma_f32_16x16x32_bf16 (B-frags sign-negated), dumps to LDS panel;
// wave-register diag Cholesky + thread-per-row TRSM as before; bf16 L out.
#define PB 32
#define PSTRIDE 260   // col-major P: banks (4c+r)%32 distinct over r

__global__ __launch_bounds__(256) void k_chol(const float* __restrict__ log_tau,
                                              float* __restrict__ ws) {
  const int d = blockIdx.x;
  const int tid = threadIdx.x;
  const int lane = tid & 63, w = tid >> 6;
  const int m16 = lane & 15, quad = lane >> 4;
  __hip_bfloat16* Lb = (__hip_bfloat16*)(ws + LB_OFF) + d * LSZ;
  const unsigned short* Lbu = (const unsigned short*)Lb;
  __shared__ float g[256];
  __shared__ float a0s[256], a1s[256];
  __shared__ float P[PB * PSTRIDE];   // col-major: P[c*PSTRIDE + r]
  __shared__ float rd_s[PB], logv[PB];
  __shared__ float logtot;

  // build g, Amu (also export Amu for k_gemm)
  float tau = expf(log_tau[d]);
  float inv2 = 1.0f / (2.0f * tau * tau);
  float lf = (float)tid;
  g[tid] = expf(-(lf * lf) * inv2);
  if (tid == 0) logtot = 0.f;
  __syncthreads();
  {
    float b = g[255];
    float det = 1.0f - b * b;
    float a0 = 0.f, a1 = 0.f;
    if (tid < Nn) {
      float kp0 = g[tid + 1], kp1 = g[254 - tid];
      a0 = (kp0 - b * kp1) / det;
      a1 = (kp1 - b * kp0) / det;
    }
    a0s[tid] = a0; a1s[tid] = a1;
    ws[AMU0_OFF + d * 256 + tid] = a0;
    ws[AMU1_OFF + d * 256 + tid] = a1;
  }
  __syncthreads();

  for (int p = 0; p < 8; ++p) {
    const int j0 = p * PB;
    const int m = Nn - j0;
    const int bw = (m < PB) ? m : PB;

    // ---- per-wave: build Schur panel slab (64 rows x 32 cols) ----
    if (w * 64 < m) {
      f32x4 acc[4][2];
#pragma unroll
      for (int ti = 0; ti < 4; ++ti)
#pragma unroll
        for (int tc = 0; tc < 2; ++tc) {
#pragma unroll
          for (int rg = 0; rg < 4; ++rg) {
            int rl = w * 64 + ti * 16 + quad * 4 + rg;
            float v = 0.f;
            if (rl < m) {
              int t = j0 + rl;                 // < Nn
              int s = j0 + tc * 16 + m16;      // <= 255 (junk cols ok)
              int lag = t - s; lag = lag < 0 ? -lag : lag;
              int e1 = s + 1 > 255 ? 255 : s + 1;
              int e2 = 254 - s < 0 ? 0 : 254 - s;
              v = g[lag] - a0s[t] * g[e1] - a1s[t] * g[e2];
              if (t == s) v += 1e-5f;
            }
            acc[ti][tc][rg] = v;
          }
        }
      // history subtraction: acc += Lrows * (-Lcols)^T over k = 0..j0
      for (int kk = 0; kk < p; ++kk) {
        const int k0 = kk * 32;
        short8 bfr[2];
#pragma unroll
        for (int tc = 0; tc < 2; ++tc) {
          int row = j0 + tc * 16 + m16;        // <= 255
          union { short8 s; unsigned int u[4]; } nb;
          nb.s = *(const short8*)&Lbu[row * 256 + k0 + quad * 8];
          nb.u[0] ^= 0x80008000u; nb.u[1] ^= 0x80008000u;
          nb.u[2] ^= 0x80008000u; nb.u[3] ^= 0x80008000u;
          bfr[tc] = nb.s;
        }
        short8 afr[4];
#pragma unroll
        for (int ti = 0; ti < 4; ++ti) {
          int row = j0 + w * 64 + ti * 16 + m16;
          if (row > 255) row = 255;            // row 255 is all-zero
          afr[ti] = *(const short8*)&Lbu[row * 256 + k0 + quad * 8];
        }
#pragma unroll
        for (int ti = 0; ti < 4; ++ti)
#pragma unroll
          for (int tc = 0; tc < 2; ++tc)
            acc[ti][tc] = __builtin_amdgcn_mfma_f32_16x16x32_bf16(afr[ti], bfr[tc], acc[ti][tc], 0, 0, 0);
      }
      // dump slab to LDS panel (D layout: row = quad*4+rg, col = m16)
#pragma unroll
      for (int ti = 0; ti < 4; ++ti)
#pragma unroll
        for (int tc = 0; tc < 2; ++tc)
#pragma unroll
          for (int rg = 0; rg < 4; ++rg) {
            int rl = w * 64 + ti * 16 + quad * 4 + rg;
            if (rl < m) P[(tc * 16 + m16) * PSTRIDE + rl] = acc[ti][tc][rg];
          }
    }
    __syncthreads();

    // ---- phase A: single-wave register Cholesky of 32x32 diag ----
    if (tid < PB) {
      const int r = tid;
      float a[PB];
#pragma unroll
      for (int c = 0; c < PB; ++c) a[c] = P[c * PSTRIDE + r];
      float dr = 1.0f;
#pragma unroll
      for (int j = 0; j < PB; ++j) {
        float pj = __shfl(a[j], j);
        if (r == j) dr = pj;
        float s = a[j] * (1.0f / pj);
#pragma unroll
        for (int k = j + 1; k < PB; ++k)
          a[k] -= s * __shfl(a[j], k);
      }
      float rinv = 1.0f / sqrtf(dr);
      rd_s[r] = rinv;
      logv[r] = (r < bw) ? 0.5f * logf(fabsf(dr)) : 0.f;
      if (r < m) {
        __hip_bfloat16* lbrow = Lb + (j0 + r) * 256 + j0;
#pragma unroll
        for (int c = 0; c < PB; ++c) {
          float sc = __shfl(rinv, c);
          float v = 0.f;
          if (c < bw) {
            if (c < r)       v = a[c] * sc;
            else if (c == r) v = sqrtf(dr);
          }
          P[c * PSTRIDE + r] = v;
          lbrow[c] = __float2bfloat16(v);
        }
      }
    }
    __syncthreads();
    if (tid == 0) {
      float s = logtot;
      for (int j2 = 0; j2 < bw; ++j2) s += logv[j2];
      logtot = s;
    }

    // ---- TRSM: rows PB..m-1, thread-per-row, float4 column reads ----
    const int nrows = m - bw;               // >0 only when bw==PB
    if (tid < nrows) {
      const int ri = PB + tid;
      float a[PB];
#pragma unroll
      for (int c = 0; c < PB; ++c) a[c] = P[c * PSTRIDE + ri];
      const float4* P4 = (const float4*)P;
#pragma unroll
      for (int j = 0; j < PB; ++j) {
        float aj = a[j] * rd_s[j];
        a[j] = aj;
#pragma unroll
        for (int q = 0; q < PB / 4; ++q) {
          if (4 * q + 3 <= j) continue;     // compile-time prune
          float4 col = P4[j * (PSTRIDE / 4) + q];   // L[4q..4q+3][j], broadcast
          if (4 * q + 0 > j) a[4 * q + 0] -= aj * col.x;
          if (4 * q + 1 > j) a[4 * q + 1] -= aj * col.y;
          if (4 * q + 2 > j) a[4 * q + 2] -= aj * col.z;
          if (4 * q + 3 > j) a[4 * q + 3] -= aj * col.w;
        }
      }
      __hip_bfloat16* lbrow = Lb + (j0 + ri) * 256 + j0;
#pragma unroll
      for (int c = 0; c < PB; ++c)
        lbrow[c] = __float2bfloat16(a[c]);
    }
    __syncthreads();   // Lb writes drained (vmcnt(0) before barrier) for next panel's reads
  }
  if (tid == 0) ws[PLD_OFF + d] = logtot;
}

// ---------------- K3: logdet reduce + scalar output ----------------
__global__ void k_logdet(const float* __restrict__ ws, const float* __restrict__ sldj,
                         float* __restrict__ out) {
  int tid = threadIdx.x;  // 64 threads
  float v = ws[PLD_OFF + tid];
  for (int off = 32; off > 0; off >>= 1) v += __shfl_down(v, off);
  if (tid == 0) out[8388608] = sldj[0] + v;   // Cc*ZSTRIDE
}

// ---------------- K4: MFMA bf16 GEMM: out[c,1+t] = sum_s z[c,s]*L[t,s] + mu ----
__global__ __launch_bounds__(256) void k_gemm(const float* __restrict__ z,
                                              const float* __restrict__ ws,
                                              float* __restrict__ out) {
  const int d = blockIdx.z;
  const int t0 = blockIdx.y * 128;
  const int c0 = blockIdx.x * 128;
  const int tid = threadIdx.x;
  const unsigned short* zb = (const unsigned short*)ws + d * (512 * 256);
  const unsigned short* lb = (const unsigned short*)(ws + LB_OFF) + d * LSZ;
  __shared__ unsigned short As[128 * 32];   // [c][s] bf16
  __shared__ unsigned short Bs[128 * 32];   // [t][s] bf16
  f32x4 acc[4][4];
#pragma unroll
  for (int mi = 0; mi < 4; ++mi)
#pragma unroll
    for (int ni = 0; ni < 4; ++ni)
      acc[mi][ni] = (f32x4){0.f, 0.f, 0.f, 0.f};

  const int l = tid & 63, w = tid >> 6;
  const int wm = w & 1, wn = w >> 1;       // wave tile: c += wm*64, t += wn*64
  const int m16 = l & 15, quad = l >> 4;

  const int nks = (blockIdx.y == 0) ? 4 : 8;   // L[t<128][s>=128]==0 -> skip
  for (int ks = 0; ks < nks; ++ks) {
    const int s0 = ks * 32;
#pragma unroll
    for (int i = 0; i < 2; ++i) {
      int e = i * 256 + tid;
      int row = e >> 2, half = e & 3;      // 4x16B chunks per 32-bf16 row
      GLD16(zb + (c0 + row) * 256 + s0 + half * 8, &As[e * 8]);
      GLD16(lb + (t0 + row) * 256 + s0 + half * 8, &Bs[e * 8]);
    }
    __syncthreads();
    short8 af[4], bf[4];
#pragma unroll
    for (int mi = 0; mi < 4; ++mi)
      af[mi] = *(const short8*)&As[(wm * 64 + mi * 16 + m16) * 32 + quad * 8];
#pragma unroll
    for (int ni = 0; ni < 4; ++ni)
      bf[ni] = *(const short8*)&Bs[(wn * 64 + ni * 16 + m16) * 32 + quad * 8];
#pragma unroll
    for (int mi = 0; mi < 4; ++mi)
#pragma unroll
      for (int ni = 0; ni < 4; ++ni)
        acc[mi][ni] = __builtin_amdgcn_mfma_f32_16x16x32_bf16(af[mi], bf[ni], acc[mi][ni], 0, 0, 0);
    __syncthreads();
  }

  // epilogue: + Amu0[t]*z[c,0] + Amu1[t]*z[c,255]; store
  const float* Amu0 = ws + AMU0_OFF + d * 256;
  const float* Amu1 = ws + AMU1_OFF + d * 256;
  float a0v[4], a1v[4];
#pragma unroll
  for (int ni = 0; ni < 4; ++ni) {
    int t_ = t0 + wn * 64 + ni * 16 + m16;
    a0v[ni] = Amu0[t_]; a1v[ni] = Amu1[t_];
  }
#pragma unroll
  for (int mi = 0; mi < 4; ++mi) {
#pragma unroll
    for (int rg = 0; rg < 4; ++rg) {
      int c_ = c0 + wm * 64 + mi * 16 + quad * 4 + rg;
      const float* zc = z + c_ * ZSTRIDE + d * Tt;
      float z0 = zc[0], z1 = zc[255];
      float* op = out + c_ * ZSTRIDE + d * Tt + 1;
#pragma unroll
      for (int ni = 0; ni < 4; ++ni) {
        int t_ = t0 + wn * 64 + ni * 16 + m16;
        float v = acc[mi][ni][rg] + a0v[ni] * z0 + a1v[ni] * z1;
        if (t_ < Nn) op[t_] = v;
      }
    }
  }
}

extern "C" void kernel_launch(void* const* d_in, const int* in_sizes, int n_in,
                              void* d_out, int out_size, void* d_ws, size_t ws_size,
                              hipStream_t stream) {
  const float* z = (const float*)d_in[0];
  const float* sldj = (const float*)d_in[1];
  const float* log_tau = (const float*)d_in[2];
  float* out = (float*)d_out;
  float* ws = (float*)d_ws;

  hipLaunchKernelGGL(k_zero, dim3(2048), dim3(256), 0, stream, ws);
  hipLaunchKernelGGL(k_zcast, dim3(8192), dim3(256), 0, stream, z, ws, out);
  hipLaunchKernelGGL(k_chol, dim3(Dd), dim3(256), 0, stream, log_tau, ws);
  hipLaunchKernelGGL(k_logdet, dim3(1), dim3(64), 0, stream, ws, sldj, out);
  hipLaunchKernelGGL(k_gemm, dim3(4, 2, Dd), dim3(256), 0, stream, z, ws, out);
}